// Round 1
// baseline (252.190 us; speedup 1.0000x reference)
//
#include <hip/hip_runtime.h>
#include <hip/hip_bf16.h>
#include <stdint.h>

// EdgeMessage: message[e,m] = sum_v (edges[e,:]@W[m*64+v,:] + b[m*64+v]) * vertices[e,v]
// Fused outer-product GEMM: C[e,m] = sum_{k'} A[e,k'] B[k',m],
//   A[e, v*128+kk] = V[e,v]*X[e,kk]  (on-the-fly, bf16-truncated via v_perm)
//   B[k', m]       = W[m*64+v, kk]   == row-major W rows, contiguous 16B frags
// Bias handled as 2 extra K-steps (A=V, B=b).

typedef __attribute__((ext_vector_type(8))) short bf16x8;
typedef __attribute__((ext_vector_type(4))) float f32x4;

#define MSG_D 64
#define VTX_D 64
#define EDG_D 128
#define EPB 128          // edges per block: 4 waves x 32
#define LDS_ROW 136      // ushorts per LDS row (128 data + 8 pad -> 2-way banks only)

__device__ __forceinline__ unsigned pk_bf16_trunc(float lo, float hi) {
  // pack two f32 into two bf16 (truncate): take high halves of each
  return __builtin_amdgcn_perm(__float_as_uint(hi), __float_as_uint(lo), 0x07060302u);
}

// ---- prep: convert W (nW) and b (nb) fp32 -> bf16 (RNE) into workspace ----
__global__ void prep_bf16(const float* __restrict__ W, const float* __restrict__ b,
                          __hip_bfloat16* __restrict__ Wb, __hip_bfloat16* __restrict__ bb,
                          int nW, int nb) {
  int i = blockIdx.x * blockDim.x + threadIdx.x;
  if (i < nW) {
    Wb[i] = __float2bfloat16(W[i]);
  } else {
    int j = i - nW;
    if (j < nb) bb[j] = __float2bfloat16(b[j]);
  }
}

// ---- main fused MFMA kernel ----
__global__ void __launch_bounds__(256)
edge_msg_mfma(const float* __restrict__ Vtx, const float* __restrict__ Xe,
              const __hip_bfloat16* __restrict__ Wb, const __hip_bfloat16* __restrict__ bb,
              float* __restrict__ out, int E)
{
  __shared__ unsigned short lds[2][64 * LDS_ROW];   // double-buffered W chunk [64 m][128 kk]

  const int tid  = threadIdx.x;
  const int lane = tid & 63;
  const int wv   = tid >> 6;
  const int q    = lane >> 4;   // quad id 0..3
  const int ln   = lane & 15;

  const int ebase = blockIdx.x * EPB + wv * 32;

  // ---- preload this lane's X fragments into registers (f32) ----
  // A-frag for m-tile t, sub s: A[e=ebase+16t+ln][kk = s*32 + q*8 + j], j=0..7
  float4 xa[2][4], xb[2][4];
  const float* vr[2];
  #pragma unroll
  for (int t = 0; t < 2; ++t) {
    int e  = ebase + 16 * t + ln;
    int er = e < E ? e : (E - 1);
    const float* xrow = Xe + (size_t)er * EDG_D;
    #pragma unroll
    for (int s = 0; s < 4; ++s) {
      int c = s * 32 + q * 8;
      xa[t][s] = *(const float4*)(xrow + c);
      xb[t][s] = *(const float4*)(xrow + c + 4);
    }
    vr[t] = Vtx + (size_t)er * VTX_D;
  }

  f32x4 acc[2][4];
  #pragma unroll
  for (int t = 0; t < 2; ++t)
    #pragma unroll
    for (int n = 0; n < 4; ++n)
      acc[t][n] = (f32x4){0.f, 0.f, 0.f, 0.f};

  // ---- W staging: thread handles 64B of the 16KB chunk; row m = tid>>2 ----
  const int srow   = tid >> 2;
  const int schunk = tid & 3;
  // W viewed as B' [64 m][8192 k']: row m = W[m*64 .. m*64+64, :] flattened (contiguous)
  const char* wptr = (const char*)Wb + ((size_t)srow * 8192 + (size_t)schunk * 32) * 2;
  const int sdoff  = srow * LDS_ROW + schunk * 32;  // ushort offset (row padded)

  // prologue: stage v = 0 into buffer 0
  {
    uint4 r0 = *(const uint4*)(wptr + 0);
    uint4 r1 = *(const uint4*)(wptr + 16);
    uint4 r2 = *(const uint4*)(wptr + 32);
    uint4 r3 = *(const uint4*)(wptr + 48);
    unsigned short* p = &lds[0][sdoff];
    *(uint4*)(p + 0)  = r0;
    *(uint4*)(p + 8)  = r1;
    *(uint4*)(p + 16) = r2;
    *(uint4*)(p + 24) = r3;
  }
  float vv0 = vr[0][0];
  float vv1 = vr[1][0];
  __syncthreads();

  for (int v = 0; v < 64; ++v) {
    uint4 r0, r1, r2, r3;
    float nv0 = vv0, nv1 = vv1;
    const bool more = (v < 63);
    if (more) {  // prefetch next W chunk + next V scalars
      const char* g = wptr + (size_t)(v + 1) * 256;
      r0 = *(const uint4*)(g + 0);
      r1 = *(const uint4*)(g + 16);
      r2 = *(const uint4*)(g + 32);
      r3 = *(const uint4*)(g + 48);
      nv0 = vr[0][v + 1];
      nv1 = vr[1][v + 1];
    }

    const unsigned short* buf = &lds[v & 1][0];
    #pragma unroll
    for (int s = 0; s < 4; ++s) {
      union { bf16x8 v8; unsigned u[4]; } af0, af1;
      {
        float4 a = xa[0][s], b2 = xb[0][s];
        af0.u[0] = pk_bf16_trunc(vv0 * a.x,  vv0 * a.y);
        af0.u[1] = pk_bf16_trunc(vv0 * a.z,  vv0 * a.w);
        af0.u[2] = pk_bf16_trunc(vv0 * b2.x, vv0 * b2.y);
        af0.u[3] = pk_bf16_trunc(vv0 * b2.z, vv0 * b2.w);
      }
      {
        float4 a = xa[1][s], b2 = xb[1][s];
        af1.u[0] = pk_bf16_trunc(vv1 * a.x,  vv1 * a.y);
        af1.u[1] = pk_bf16_trunc(vv1 * a.z,  vv1 * a.w);
        af1.u[2] = pk_bf16_trunc(vv1 * b2.x, vv1 * b2.y);
        af1.u[3] = pk_bf16_trunc(vv1 * b2.z, vv1 * b2.w);
      }
      #pragma unroll
      for (int n = 0; n < 4; ++n) {
        int m = n * 16 + ln;
        const bf16x8 bf = *(const bf16x8*)((const char*)buf + m * (LDS_ROW * 2) + s * 64 + q * 16);
        acc[0][n] = __builtin_amdgcn_mfma_f32_16x16x32_bf16(af0.v8, bf, acc[0][n], 0, 0, 0);
        acc[1][n] = __builtin_amdgcn_mfma_f32_16x16x32_bf16(af1.v8, bf, acc[1][n], 0, 0, 0);
      }
    }

    if (more) {
      unsigned short* p = &lds[(v + 1) & 1][sdoff];
      *(uint4*)(p + 0)  = r0;
      *(uint4*)(p + 8)  = r1;
      *(uint4*)(p + 16) = r2;
      *(uint4*)(p + 24) = r3;
    }
    __syncthreads();
    vv0 = nv0; vv1 = nv1;
  }

  // ---- bias: 2 extra K-steps, A = V[e, 32s + q*8 + j], B = b[m*64 + ...] ----
  #pragma unroll
  for (int s = 0; s < 2; ++s) {
    union { bf16x8 v8; unsigned u[4]; } af0, af1;
    {
      float4 a  = *(const float4*)(vr[0] + s * 32 + q * 8);
      float4 b2 = *(const float4*)(vr[0] + s * 32 + q * 8 + 4);
      af0.u[0] = pk_bf16_trunc(a.x,  a.y);
      af0.u[1] = pk_bf16_trunc(a.z,  a.w);
      af0.u[2] = pk_bf16_trunc(b2.x, b2.y);
      af0.u[3] = pk_bf16_trunc(b2.z, b2.w);
    }
    {
      float4 a  = *(const float4*)(vr[1] + s * 32 + q * 8);
      float4 b2 = *(const float4*)(vr[1] + s * 32 + q * 8 + 4);
      af1.u[0] = pk_bf16_trunc(a.x,  a.y);
      af1.u[1] = pk_bf16_trunc(a.z,  a.w);
      af1.u[2] = pk_bf16_trunc(b2.x, b2.y);
      af1.u[3] = pk_bf16_trunc(b2.z, b2.w);
    }
    #pragma unroll
    for (int n = 0; n < 4; ++n) {
      int m = n * 16 + ln;
      const bf16x8 bf = *(const bf16x8*)((const char*)bb + ((size_t)m * 64 + s * 32 + q * 8) * 2);
      acc[0][n] = __builtin_amdgcn_mfma_f32_16x16x32_bf16(af0.v8, bf, acc[0][n], 0, 0, 0);
      acc[1][n] = __builtin_amdgcn_mfma_f32_16x16x32_bf16(af1.v8, bf, acc[1][n], 0, 0, 0);
    }
  }

  // ---- store: C layout col=lane&15 (m), row=q*4+r (e) [m89-verified] ----
  #pragma unroll
  for (int t = 0; t < 2; ++t) {
    #pragma unroll
    for (int r = 0; r < 4; ++r) {
      int e = ebase + 16 * t + 4 * q + r;
      if (e < E) {
        float* orow = out + (size_t)e * MSG_D;
        #pragma unroll
        for (int n = 0; n < 4; ++n)
          orow[n * 16 + ln] = acc[t][n][r];
      }
    }
  }
}

// ---- fallback (only if workspace too small): exact fp32, slow but correct ----
__global__ void edge_msg_naive(const float* __restrict__ Vtx, const float* __restrict__ Xe,
                               const float* __restrict__ W, const float* __restrict__ b,
                               float* __restrict__ out, int E) {
  __shared__ float xs[EDG_D];
  __shared__ float vs[VTX_D];
  int e = blockIdx.x;
  int m = threadIdx.x;
  for (int i = m; i < EDG_D; i += 64) xs[i] = Xe[(size_t)e * EDG_D + i];
  for (int i = m; i < VTX_D; i += 64) vs[i] = Vtx[(size_t)e * VTX_D + i];
  __syncthreads();
  float s = 0.f;
  for (int v = 0; v < VTX_D; ++v) {
    const float* wr = W + (size_t)(m * 64 + v) * EDG_D;
    float p = b[m * 64 + v];
    for (int k = 0; k < EDG_D; ++k) p += xs[k] * wr[k];
    s += p * vs[v];
  }
  out[(size_t)e * MSG_D + m] = s;
}

extern "C" void kernel_launch(void* const* d_in, const int* in_sizes, int n_in,
                              void* d_out, int out_size, void* d_ws, size_t ws_size,
                              hipStream_t stream) {
  const float* Vtx = (const float*)d_in[0];   // [E, 64]
  const float* Xe  = (const float*)d_in[1];   // [E, 128]
  const float* W   = (const float*)d_in[2];   // [4096, 128]
  const float* b   = (const float*)d_in[3];   // [4096]
  float* out = (float*)d_out;

  const int E  = in_sizes[0] / VTX_D;
  const int nW = in_sizes[2];
  const int nb = in_sizes[3];
  const size_t need = (size_t)(nW + nb) * sizeof(__hip_bfloat16);

  if (ws_size < need) {
    edge_msg_naive<<<E, 64, 0, stream>>>(Vtx, Xe, W, b, out, E);
    return;
  }

  __hip_bfloat16* Wb = (__hip_bfloat16*)d_ws;
  __hip_bfloat16* bb = Wb + nW;

  int nTot = nW + nb;
  prep_bf16<<<(nTot + 255) / 256, 256, 0, stream>>>(W, b, Wb, bb, nW, nb);

  int blocks = (E + EPB - 1) / EPB;
  edge_msg_mfma<<<blocks, 256, 0, stream>>>(Vtx, Xe, Wb, bb, out, E);
}

// Round 3
// 251.391 us; speedup vs baseline: 1.0032x; 1.0032x over previous
//
#include <hip/hip_runtime.h>
#include <hip/hip_bf16.h>
#include <stdint.h>

// EdgeMessage: message[e,m] = sum_v (edges[e,:]@W[m*64+v,:] + b[m*64+v]) * vertices[e,v]
// Fused outer-product GEMM: C[e,m] = sum_{k'} A[e,k'] B[k',m],
//   A[e, v*128+kk] = V[e,v]*X[e,kk]  (on-the-fly, bf16-truncated via v_perm)
//   B[k', m]       = W[m*64+v, kk]   == row-major W rows, contiguous 16B frags
// Bias handled as 2 extra K-steps (A=V, B=b).
// R2: XOR-swizzled LDS layout (16B-chunk c stored at c ^ (row&7), 256B rows)
//     -> balanced 8-lanes-per-4-bank-group on both read and write sides.
// R3: fix prologue double-counting schunk offset (wbase already includes it).

typedef __attribute__((ext_vector_type(8))) short bf16x8;
typedef __attribute__((ext_vector_type(4))) float f32x4;

#define MSG_D 64
#define VTX_D 64
#define EDG_D 128
#define EPB 128          // edges per block: 4 waves x 32

__device__ __forceinline__ unsigned pk_bf16_trunc(float lo, float hi) {
  // pack two f32 into two bf16 (truncate): take high halves of each
  return __builtin_amdgcn_perm(__float_as_uint(hi), __float_as_uint(lo), 0x07060302u);
}

// ---- prep: convert W (nW) and b (nb) fp32 -> bf16 (RNE) into workspace ----
__global__ void prep_bf16(const float* __restrict__ W, const float* __restrict__ b,
                          __hip_bfloat16* __restrict__ Wb, __hip_bfloat16* __restrict__ bb,
                          int nW, int nb) {
  int i = blockIdx.x * blockDim.x + threadIdx.x;
  if (i < nW) {
    Wb[i] = __float2bfloat16(W[i]);
  } else {
    int j = i - nW;
    if (j < nb) bb[j] = __float2bfloat16(b[j]);
  }
}

// ---- main fused MFMA kernel ----
__global__ void __launch_bounds__(256)
edge_msg_mfma(const float* __restrict__ Vtx, const float* __restrict__ Xe,
              const __hip_bfloat16* __restrict__ Wb, const __hip_bfloat16* __restrict__ bb,
              float* __restrict__ out, int E)
{
  // double-buffered W chunk [64 m][128 kk], 256B rows, XOR-swizzled 16B chunks
  __shared__ unsigned short lds[2][64 * 128];

  const int tid  = threadIdx.x;
  const int lane = tid & 63;
  const int wv   = tid >> 6;
  const int q    = lane >> 4;   // quad id 0..3
  const int ln   = lane & 15;

  const int ebase = blockIdx.x * EPB + wv * 32;

  // ---- preload this lane's X fragments into registers (f32) ----
  float4 xa[2][4], xb[2][4];
  const float* vr[2];
  #pragma unroll
  for (int t = 0; t < 2; ++t) {
    int e  = ebase + 16 * t + ln;
    int er = e < E ? e : (E - 1);
    const float* xrow = Xe + (size_t)er * EDG_D;
    #pragma unroll
    for (int s = 0; s < 4; ++s) {
      int c = s * 32 + q * 8;
      xa[t][s] = *(const float4*)(xrow + c);
      xb[t][s] = *(const float4*)(xrow + c + 4);
    }
    vr[t] = Vtx + (size_t)er * VTX_D;
  }

  f32x4 acc[2][4];
  #pragma unroll
  for (int t = 0; t < 2; ++t)
    #pragma unroll
    for (int n = 0; n < 4; ++n)
      acc[t][n] = (f32x4){0.f, 0.f, 0.f, 0.f};

  // ---- W staging: thread covers 64B of the 16KB chunk; row m = tid>>2 ----
  const int srow   = tid >> 2;
  const int schunk = tid & 3;
  const unsigned short* wbase = (const unsigned short*)Wb + (size_t)srow * 8192 + schunk * 32;
  // swizzled LDS destinations for the 4 16B chunks this thread stages
  int sdst[4];
  #pragma unroll
  for (int j = 0; j < 4; ++j) {
    int c  = schunk * 4 + j;
    int cp = (c & 8) | ((c ^ (srow & 7)) & 7);
    sdst[j] = srow * 128 + cp * 8;
  }

  // swizzled read-chunk index per s (same for all n since m&7 == ln&7)
  int rcp[4];
  #pragma unroll
  for (int s = 0; s < 4; ++s) {
    int c  = s * 4 + q;
    rcp[s] = (c & 8) | ((c ^ (ln & 7)) & 7);
  }

  // prologue: stage v = 0 into buffer 0 (wbase already includes schunk*32)
  {
    #pragma unroll
    for (int j = 0; j < 4; ++j) {
      uint4 r = *(const uint4*)(wbase + j * 8);
      *(uint4*)(&lds[0][sdst[j]]) = r;
    }
  }
  float vv0 = vr[0][0];
  float vv1 = vr[1][0];
  __syncthreads();

  for (int v = 0; v < 64; ++v) {
    uint4 r0, r1, r2, r3;
    float nv0 = vv0, nv1 = vv1;
    const bool more = (v < 63);
    if (more) {  // prefetch next W chunk + next V scalars
      const unsigned short* g = wbase + (size_t)(v + 1) * 128;
      r0 = *(const uint4*)(g + 0);
      r1 = *(const uint4*)(g + 8);
      r2 = *(const uint4*)(g + 16);
      r3 = *(const uint4*)(g + 24);
      nv0 = vr[0][v + 1];
      nv1 = vr[1][v + 1];
    }

    const unsigned short* buf = &lds[v & 1][0];
    #pragma unroll
    for (int s = 0; s < 4; ++s) {
      union { bf16x8 v8; unsigned u[4]; } af0, af1;
      {
        float4 a = xa[0][s], b2 = xb[0][s];
        af0.u[0] = pk_bf16_trunc(vv0 * a.x,  vv0 * a.y);
        af0.u[1] = pk_bf16_trunc(vv0 * a.z,  vv0 * a.w);
        af0.u[2] = pk_bf16_trunc(vv0 * b2.x, vv0 * b2.y);
        af0.u[3] = pk_bf16_trunc(vv0 * b2.z, vv0 * b2.w);
      }
      {
        float4 a = xa[1][s], b2 = xb[1][s];
        af1.u[0] = pk_bf16_trunc(vv1 * a.x,  vv1 * a.y);
        af1.u[1] = pk_bf16_trunc(vv1 * a.z,  vv1 * a.w);
        af1.u[2] = pk_bf16_trunc(vv1 * b2.x, vv1 * b2.y);
        af1.u[3] = pk_bf16_trunc(vv1 * b2.z, vv1 * b2.w);
      }
      const unsigned short* pbase = buf + ln * 128 + rcp[s] * 8;
      #pragma unroll
      for (int n = 0; n < 4; ++n) {
        const bf16x8 bf = *(const bf16x8*)(pbase + n * 2048);
        acc[0][n] = __builtin_amdgcn_mfma_f32_16x16x32_bf16(af0.v8, bf, acc[0][n], 0, 0, 0);
        acc[1][n] = __builtin_amdgcn_mfma_f32_16x16x32_bf16(af1.v8, bf, acc[1][n], 0, 0, 0);
      }
    }

    if (more) {
      unsigned short* p = &lds[(v + 1) & 1][0];
      *(uint4*)(p + sdst[0]) = r0;
      *(uint4*)(p + sdst[1]) = r1;
      *(uint4*)(p + sdst[2]) = r2;
      *(uint4*)(p + sdst[3]) = r3;
    }
    __syncthreads();
    vv0 = nv0; vv1 = nv1;
  }

  // ---- bias: 2 extra K-steps, A = V[e, 32s + q*8 + j], B = b[m*64 + ...] ----
  #pragma unroll
  for (int s = 0; s < 2; ++s) {
    union { bf16x8 v8; unsigned u[4]; } af0, af1;
    {
      float4 a  = *(const float4*)(vr[0] + s * 32 + q * 8);
      float4 b2 = *(const float4*)(vr[0] + s * 32 + q * 8 + 4);
      af0.u[0] = pk_bf16_trunc(a.x,  a.y);
      af0.u[1] = pk_bf16_trunc(a.z,  a.w);
      af0.u[2] = pk_bf16_trunc(b2.x, b2.y);
      af0.u[3] = pk_bf16_trunc(b2.z, b2.w);
    }
    {
      float4 a  = *(const float4*)(vr[1] + s * 32 + q * 8);
      float4 b2 = *(const float4*)(vr[1] + s * 32 + q * 8 + 4);
      af1.u[0] = pk_bf16_trunc(a.x,  a.y);
      af1.u[1] = pk_bf16_trunc(a.z,  a.w);
      af1.u[2] = pk_bf16_trunc(b2.x, b2.y);
      af1.u[3] = pk_bf16_trunc(b2.z, b2.w);
    }
    #pragma unroll
    for (int n = 0; n < 4; ++n) {
      int m = n * 16 + ln;
      const bf16x8 bf = *(const bf16x8*)((const char*)bb + ((size_t)m * 64 + s * 32 + q * 8) * 2);
      acc[0][n] = __builtin_amdgcn_mfma_f32_16x16x32_bf16(af0.v8, bf, acc[0][n], 0, 0, 0);
      acc[1][n] = __builtin_amdgcn_mfma_f32_16x16x32_bf16(af1.v8, bf, acc[1][n], 0, 0, 0);
    }
  }

  // ---- store: C layout col=lane&15 (m), row=q*4+r (e) [m89-verified] ----
  #pragma unroll
  for (int t = 0; t < 2; ++t) {
    #pragma unroll
    for (int r = 0; r < 4; ++r) {
      int e = ebase + 16 * t + 4 * q + r;
      if (e < E) {
        float* orow = out + (size_t)e * MSG_D;
        #pragma unroll
        for (int n = 0; n < 4; ++n)
          orow[n * 16 + ln] = acc[t][n][r];
      }
    }
  }
}

// ---- fallback (only if workspace too small): exact fp32, slow but correct ----
__global__ void edge_msg_naive(const float* __restrict__ Vtx, const float* __restrict__ Xe,
                               const float* __restrict__ W, const float* __restrict__ b,
                               float* __restrict__ out, int E) {
  __shared__ float xs[EDG_D];
  __shared__ float vs[VTX_D];
  int e = blockIdx.x;
  int m = threadIdx.x;
  for (int i = m; i < EDG_D; i += 64) xs[i] = Xe[(size_t)e * EDG_D + i];
  for (int i = m; i < VTX_D; i += 64) vs[i] = Vtx[(size_t)e * VTX_D + i];
  __syncthreads();
  float s = 0.f;
  for (int v = 0; v < VTX_D; ++v) {
    const float* wr = W + (size_t)(m * 64 + v) * EDG_D;
    float p = b[m * 64 + v];
    for (int k = 0; k < EDG_D; ++k) p += xs[k] * wr[k];
    s += p * vs[v];
  }
  out[(size_t)e * MSG_D + m] = s;
}

extern "C" void kernel_launch(void* const* d_in, const int* in_sizes, int n_in,
                              void* d_out, int out_size, void* d_ws, size_t ws_size,
                              hipStream_t stream) {
  const float* Vtx = (const float*)d_in[0];   // [E, 64]
  const float* Xe  = (const float*)d_in[1];   // [E, 128]
  const float* W   = (const float*)d_in[2];   // [4096, 128]
  const float* b   = (const float*)d_in[3];   // [4096]
  float* out = (float*)d_out;

  const int E  = in_sizes[0] / VTX_D;
  const int nW = in_sizes[2];
  const int nb = in_sizes[3];
  const size_t need = (size_t)(nW + nb) * sizeof(__hip_bfloat16);

  if (ws_size < need) {
    edge_msg_naive<<<E, 64, 0, stream>>>(Vtx, Xe, W, b, out, E);
    return;
  }

  __hip_bfloat16* Wb = (__hip_bfloat16*)d_ws;
  __hip_bfloat16* bb = Wb + nW;

  int nTot = nW + nb;
  prep_bf16<<<(nTot + 255) / 256, 256, 0, stream>>>(W, b, Wb, bb, nW, nb);

  int blocks = (E + EPB - 1) / EPB;
  edge_msg_mfma<<<blocks, 256, 0, stream>>>(Vtx, Xe, Wb, bb, out, E);
}